// Round 2
// baseline (934.786 us; speedup 1.0000x reference)
//
#include <hip/hip_runtime.h>
#include <math.h>

// ---------------------------------------------------------------------------
// MPConv round 4: dst-sorted edges + run-reduced scatter.
//  - prep: W1,W2 f32 -> bf16 transposed; x f32 -> bf16 [N][64]
//  - sort: counting sort of edges by dst j (hist -> scan -> perm)
//  - main: 4 waves x 64 edges. GEMM1 (bf16 MFMA), LN+GELU, GEMM2.
//    MODE 2: messages -> LDS f32 (stride 66, conflict-free), walk dst-sorted
//    rows accumulating per-channel run sums, 1 coalesced atomic per run
//    (~E/deg atomics instead of E*64).
//    Per-wave disjoint LDS regions (Hlds/Hf union) -> zero barriers.
// ---------------------------------------------------------------------------

using short8 = __attribute__((ext_vector_type(8))) short;
using f32x4  = __attribute__((ext_vector_type(4))) float;

#define LDH 72        // bf16 H-tile stride (64+8)
#define WREG 9472     // per-wave LDS bytes: max(64*72*2, 32*66*4)=9216, +64*4 dstL, 16B-aligned
#define SMEM_BYTES (4 * WREG)   // 37,888

static __device__ __forceinline__ short f2bf(float f) {
    unsigned u = __float_as_uint(f);
    u += 0x7FFFu + ((u >> 16) & 1u);        // round-to-nearest-even
    return (short)(u >> 16);
}

static __device__ __forceinline__ short8 pack8(float4 a, float4 b) {
    short8 r;
    r[0] = f2bf(a.x); r[1] = f2bf(a.y); r[2] = f2bf(a.z); r[3] = f2bf(a.w);
    r[4] = f2bf(b.x); r[5] = f2bf(b.y); r[6] = f2bf(b.z); r[7] = f2bf(b.w);
    return r;
}

// ---- weight prep: f32 [k][n] -> bf16 [n][k] ------------------------------
__global__ void prep_weights(const float* __restrict__ W1,
                             const float* __restrict__ W2,
                             short* __restrict__ Wt1,   // [64][160]
                             short* __restrict__ Wt2)   // [64][64]
{
    int t = blockIdx.x * blockDim.x + threadIdx.x;
    if (t < 160 * 64) {
        int k = t / 64, n = t % 64;
        Wt1[n * 160 + k] = f2bf(W1[t]);
    }
    int t2 = t - 160 * 64;
    if (t2 >= 0 && t2 < 64 * 64) {
        int k = t2 / 64, n = t2 % 64;
        Wt2[n * 64 + k] = f2bf(W2[t2]);
    }
}

// ---- x prep: f32 [N,64] -> bf16 [N][64] (8 elems / thread) ---------------
__global__ void prep_x_bf16(const float* __restrict__ x,
                            short* __restrict__ xbf,
                            int total8)
{
    int t = blockIdx.x * blockDim.x + threadIdx.x;
    if (t < total8) {
        const float4* xf4 = (const float4*)x;
        float4 a = xf4[2 * t];
        float4 b = xf4[2 * t + 1];
        ((short8*)xbf)[t] = pack8(a, b);
    }
}

// ---- counting sort by dst ------------------------------------------------
__global__ void hist_dst(const int* __restrict__ ei, int* __restrict__ counts, int E)
{
    int e = blockIdx.x * blockDim.x + threadIdx.x;
    if (e < E) atomicAdd(&counts[ei[E + e]], 1);
}

#define SCAN_T 1024
__global__ __launch_bounds__(SCAN_T) void scan_offsets(const int* __restrict__ counts,
                                                       int* __restrict__ offs, int N)
{
    __shared__ int part[SCAN_T];
    int t = threadIdx.x;
    int chunk = (N + SCAN_T - 1) / SCAN_T;
    int lo = t * chunk, hi = min(lo + chunk, N);
    int s = 0;
    for (int i = lo; i < hi; i++) s += counts[i];
    part[t] = s;
    __syncthreads();
    for (int d = 1; d < SCAN_T; d <<= 1) {
        int v = (t >= d) ? part[t - d] : 0;
        __syncthreads();
        part[t] += v;
        __syncthreads();
    }
    int excl = (t == 0) ? 0 : part[t - 1];
    for (int i = lo; i < hi; i++) { int c = counts[i]; offs[i] = excl; excl += c; }
}

__global__ void build_perm(const int* __restrict__ ei, int* __restrict__ offs,
                           int* __restrict__ perm, int E)
{
    int e = blockIdx.x * blockDim.x + threadIdx.x;
    if (e < E) {
        int dst = ei[E + e];
        int pos = atomicAdd(&offs[dst], 1);
        perm[pos] = e;
    }
}

// ---- main kernel ---------------------------------------------------------
// MODE 0: f32 x gather, direct per-element scatter
// MODE 1: bf16 x gather, direct per-element scatter
// MODE 2: bf16 x gather, dst-sorted edges, run-reduced scatter
template <int MODE>
__global__ __launch_bounds__(256) void mpconv_mfma(
    const float* __restrict__ x,      // [N,64]
    const short* __restrict__ xbf,    // [N][64] bf16
    const int*   __restrict__ ei,     // [2,E]
    const float* __restrict__ ea,     // [E,32]
    const short* __restrict__ Wt1,    // [64][160] bf16
    const float* __restrict__ b1,
    const float* __restrict__ gam,
    const float* __restrict__ bet,
    const short* __restrict__ Wt2,    // [64][64] bf16
    const float* __restrict__ b2,
    const int*   __restrict__ perm,   // [E] (MODE 2)
    float*       __restrict__ out,    // [N,64]
    int E)
{
    __shared__ __align__(16) char smem[SMEM_BYTES];

    const int wave = threadIdx.x >> 6;
    const int lane = threadIdx.x & 63;
    const int g    = lane >> 4;        // quad id 0..3
    const int col  = lane & 15;
    const int eb   = blockIdx.x * 256 + wave * 64;     // wave's sorted-edge base

    char* wbase = smem + wave * WREG;
    short (*Hl)[LDH] = (short (*)[LDH])wbase;   // [64][72] bf16 H (GEMM2 A)
    float (*Hf)[66]  = (float (*)[66])wbase;    // [32][66] f32 messages (aliases Hl)
    int*  dstL       = (int*)(wbase + 9216);    // [64] run destinations

    // edges whose A-rows this lane loads (row m = col in each 16-row M tile)
    int aedge[4], ii[4], jj[4];
#pragma unroll
    for (int mt = 0; mt < 4; mt++) {
        int ep = eb + mt * 16 + col;
        bool v = (ep < E);
        int epc = v ? ep : (E - 1);
        int e = (MODE == 2) ? perm[epc] : epc;
        aedge[mt] = e;
        ii[mt] = ei[e];
        jj[mt] = ei[E + e];
        if (MODE == 2 && g == 0) dstL[mt * 16 + col] = v ? jj[mt] : -1;
    }

    // per-lane channel params for its 4 columns (col + 16*nt)
    float b1c[4], gc[4], bc[4], b2c[4];
#pragma unroll
    for (int nt = 0; nt < 4; nt++) {
        int c = col + 16 * nt;
        b1c[nt] = b1[c]; gc[nt] = gam[c]; bc[nt] = bet[c]; b2c[nt] = b2[c];
    }

    // ---- GEMM1: [64,160] @ [160,64] -----------------------------------
    f32x4 acc[4][4];
#pragma unroll
    for (int mt = 0; mt < 4; mt++)
#pragma unroll
        for (int nt = 0; nt < 4; nt++)
            acc[mt][nt] = (f32x4){0.f, 0.f, 0.f, 0.f};

#pragma unroll
    for (int ks = 0; ks < 5; ks++) {
        const int k0 = ks * 32;
        const int kk = k0 + g * 8;     // this quad's k-chunk (8 wide)

        short8 afrag[4];
#pragma unroll
        for (int mt = 0; mt < 4; mt++) {
            if (MODE >= 1 && k0 < 64) {
                afrag[mt] = *(const short8*)(xbf + (size_t)ii[mt] * 64 + kk);
            } else if (MODE >= 1 && k0 < 128) {
                afrag[mt] = *(const short8*)(xbf + (size_t)jj[mt] * 64 + (kk - 64));
            } else {
                const float* s;
                if (k0 < 64)       s = x  + (size_t)ii[mt] * 64 + kk;
                else if (k0 < 128) s = x  + (size_t)jj[mt] * 64 + (kk - 64);
                else               s = ea + (size_t)aedge[mt] * 32 + (kk - 128);
                float4 a = *(const float4*)s;
                float4 b = *(const float4*)(s + 4);
                afrag[mt] = pack8(a, b);
            }
        }
        short8 bfrag[4];
#pragma unroll
        for (int nt = 0; nt < 4; nt++)
            bfrag[nt] = *(const short8*)(Wt1 + (size_t)(col + 16 * nt) * 160 + kk);

#pragma unroll
        for (int mt = 0; mt < 4; mt++)
#pragma unroll
            for (int nt = 0; nt < 4; nt++)
                acc[mt][nt] = __builtin_amdgcn_mfma_f32_16x16x32_bf16(
                    afrag[mt], bfrag[nt], acc[mt][nt], 0, 0, 0);
    }

    // ---- +b1, LayerNorm, GELU, write H to LDS -------------------------
    // C layout: row = g*4 + r, col = col + 16*nt  (within each 16x16 tile)
#pragma unroll
    for (int mt = 0; mt < 4; mt++) {
        float s[4] = {0.f, 0.f, 0.f, 0.f};
        float q[4] = {0.f, 0.f, 0.f, 0.f};
#pragma unroll
        for (int nt = 0; nt < 4; nt++) {
#pragma unroll
            for (int r = 0; r < 4; r++) {
                float v = acc[mt][nt][r] + b1c[nt];
                acc[mt][nt][r] = v;
                s[r] += v;
                q[r] += v * v;
            }
        }
#pragma unroll
        for (int m = 1; m < 16; m <<= 1) {
#pragma unroll
            for (int r = 0; r < 4; r++) {
                s[r] += __shfl_xor(s[r], m);
                q[r] += __shfl_xor(q[r], m);
            }
        }
#pragma unroll
        for (int r = 0; r < 4; r++) {
            float mu  = s[r] * (1.0f / 64.0f);
            float var = q[r] * (1.0f / 64.0f) - mu * mu;
            float inv = rsqrtf(var + 1e-5f);
            int row = mt * 16 + g * 4 + r;
#pragma unroll
            for (int nt = 0; nt < 4; nt++) {
                float h = (acc[mt][nt][r] - mu) * inv * gc[nt] + bc[nt];
                h = 0.5f * h * (1.0f + erff(h * 0.70710678118654752f));
                Hl[row][col + 16 * nt] = f2bf(h);
            }
        }
    }
    // no barrier: Hl is written and read only by this wave; LDS ops are
    // in-order per wave and the compiler must preserve store->load order
    // on the (may-alias) shared array.

    // ---- GEMM2: [64,64] @ [64,64] -------------------------------------
    f32x4 acc2[4][4];
#pragma unroll
    for (int mt = 0; mt < 4; mt++)
#pragma unroll
        for (int nt = 0; nt < 4; nt++)
            acc2[mt][nt] = (f32x4){0.f, 0.f, 0.f, 0.f};

#pragma unroll
    for (int ks = 0; ks < 2; ks++) {
        const int kk = ks * 32 + g * 8;
        short8 af[4], bf[4];
#pragma unroll
        for (int mt = 0; mt < 4; mt++)
            af[mt] = *(const short8*)&Hl[mt * 16 + col][kk];
#pragma unroll
        for (int nt = 0; nt < 4; nt++)
            bf[nt] = *(const short8*)(Wt2 + (size_t)(col + 16 * nt) * 64 + kk);
#pragma unroll
        for (int mt = 0; mt < 4; mt++)
#pragma unroll
            for (int nt = 0; nt < 4; nt++)
                acc2[mt][nt] = __builtin_amdgcn_mfma_f32_16x16x32_bf16(
                    af[mt], bf[nt], acc2[mt][nt], 0, 0, 0);
    }

    if (MODE == 2) {
        // ---- run-reduced scatter over dst-sorted rows ------------------
        // Two 32-row passes; Hf aliases Hl (GEMM2 reads are complete, and
        // per-wave LDS ordering makes the overwrite safe without a barrier).
        int cur = -1;
        float sum = 0.f;
#pragma unroll
        for (int p = 0; p < 2; p++) {
#pragma unroll
            for (int m2 = 0; m2 < 2; m2++) {
                int mt = 2 * p + m2;
#pragma unroll
                for (int nt = 0; nt < 4; nt++)
#pragma unroll
                    for (int r = 0; r < 4; r++)
                        Hf[m2 * 16 + g * 4 + r][col + 16 * nt] =
                            acc2[mt][nt][r] + b2c[nt];
            }
#pragma unroll 4
            for (int row = 0; row < 32; row++) {
                int d = dstL[p * 32 + row];      // broadcast read, wave-uniform
                float v = Hf[row][lane];         // 2-way bank alias: free
                if (d != cur) {                  // uniform branch
                    if (cur >= 0)
                        unsafeAtomicAdd(out + (size_t)cur * 64 + lane, sum);
                    cur = d; sum = 0.f;
                }
                if (d >= 0) sum += v;
            }
        }
        if (cur >= 0)
            unsafeAtomicAdd(out + (size_t)cur * 64 + lane, sum);
    } else {
        // ---- +b2 and direct scatter-add to out[j] ----------------------
#pragma unroll
        for (int mt = 0; mt < 4; mt++) {
#pragma unroll
            for (int r = 0; r < 4; r++) {
                int e = eb + mt * 16 + g * 4 + r;
                if (e < E) {
                    int dst = ei[E + e];
                    float* op = out + (size_t)dst * 64 + col;
#pragma unroll
                    for (int nt = 0; nt < 4; nt++)
                        unsafeAtomicAdd(op + 16 * nt, acc2[mt][nt][r] + b2c[nt]);
                }
            }
        }
    }
}

extern "C" void kernel_launch(void* const* d_in, const int* in_sizes, int n_in,
                              void* d_out, int out_size, void* d_ws, size_t ws_size,
                              hipStream_t stream)
{
    const float* x   = (const float*)d_in[0];
    const int*   ei  = (const int*)  d_in[1];
    const float* ea  = (const float*)d_in[2];
    const float* W1  = (const float*)d_in[3];
    const float* b1  = (const float*)d_in[4];
    const float* gam = (const float*)d_in[5];
    const float* bet = (const float*)d_in[6];
    const float* W2  = (const float*)d_in[7];
    const float* b2  = (const float*)d_in[8];
    float* out = (float*)d_out;

    const int E = in_sizes[1] / 2;
    const int N = in_sizes[0] / 64;

    // workspace layout:
    //   Wt1 bf16[64][160] | Wt2 bf16[64][64] | xbf bf16[N][64] |
    //   counts int[N] | offs int[N] | perm int[E]
    short* Wt1 = (short*)d_ws;
    short* Wt2 = Wt1 + 160 * 64;
    const size_t woff = (size_t)(160 * 64 + 64 * 64) * sizeof(short);   // 28,672
    short* xbf = (short*)((char*)d_ws + woff);
    const size_t need_xbf = woff + (size_t)N * 64 * sizeof(short);
    const size_t soff = (need_xbf + 255) & ~(size_t)255;
    int* counts = (int*)((char*)d_ws + soff);
    int* offs   = counts + N;
    int* perm   = offs + N;
    const size_t need_sort = soff + (size_t)N * 8 + (size_t)E * 4;

    const int mode = (ws_size >= need_sort) ? 2 : (ws_size >= need_xbf ? 1 : 0);

    hipMemsetAsync(d_out, 0, (size_t)out_size * sizeof(float), stream);

    {
        int total = 160 * 64 + 64 * 64;
        int grid = (total + 255) / 256;
        hipLaunchKernelGGL(prep_weights, dim3(grid), dim3(256), 0, stream,
                           W1, W2, Wt1, Wt2);
    }
    if (mode >= 1) {
        int total8 = N * 8;
        int grid = (total8 + 255) / 256;
        hipLaunchKernelGGL(prep_x_bf16, dim3(grid), dim3(256), 0, stream,
                           x, xbf, total8);
    }
    if (mode == 2) {
        hipMemsetAsync(counts, 0, (size_t)N * sizeof(int), stream);
        int gridE = (E + 255) / 256;
        hipLaunchKernelGGL(hist_dst, dim3(gridE), dim3(256), 0, stream,
                           ei, counts, E);
        hipLaunchKernelGGL(scan_offsets, dim3(1), dim3(SCAN_T), 0, stream,
                           counts, offs, N);
        hipLaunchKernelGGL(build_perm, dim3(gridE), dim3(256), 0, stream,
                           ei, offs, perm, E);
    }
    {
        int grid = (E + 255) / 256;
        if (mode == 2)
            hipLaunchKernelGGL(mpconv_mfma<2>, dim3(grid), dim3(256), 0, stream,
                               x, xbf, ei, ea, Wt1, b1, gam, bet, Wt2, b2, perm, out, E);
        else if (mode == 1)
            hipLaunchKernelGGL(mpconv_mfma<1>, dim3(grid), dim3(256), 0, stream,
                               x, xbf, ei, ea, Wt1, b1, gam, bet, Wt2, b2, perm, out, E);
        else
            hipLaunchKernelGGL(mpconv_mfma<0>, dim3(grid), dim3(256), 0, stream,
                               x, xbf, ei, ea, Wt1, b1, gam, bet, Wt2, b2, perm, out, E);
    }
}